// Round 17
// baseline (1151.402 us; speedup 1.0000x reference)
//
#include <hip/hip_runtime.h>
#include <math.h>

#define NB 16       // batch
#define NH 256      // hidden dim
#define NLV 12      // levels
#define NN 4095     // nodes
#define OUTW 512    // output last-dim (2H)

typedef unsigned short u16;
typedef unsigned int u32;
typedef __attribute__((ext_vector_type(4))) float f32x4;
typedef __attribute__((ext_vector_type(8))) short bf16x8;

// Fast gate math: v_exp_f32 + v_rcp_f32 (limits exact, no NaN paths).
__device__ __forceinline__ float sigf(float x){
  return __fdividef(1.0f, 1.0f + __expf(-x));
}
__device__ __forceinline__ float tanh_fast(float x){
  return 1.0f - __fdividef(2.0f, 1.0f + __expf(2.0f * x));
}

__device__ __forceinline__ u16 f2bf(float x){
  unsigned int u = __float_as_uint(x);
  return (u16)((u + 0x7fffu + ((u >> 16) & 1u)) >> 16);
}
__device__ __forceinline__ float bf2f(u16 h){
  return __uint_as_float(((unsigned int)h) << 16);
}

// async global->LDS, 16B per lane; LDS dest = wave-uniform base + lane*16
__device__ __forceinline__ void gload16(const void* g, void* l){
  __builtin_amdgcn_global_load_lds(
      (const __attribute__((address_space(1))) unsigned int*)g,
      (__attribute__((address_space(3))) unsigned int*)l, 16, 0, 0);
}

// =========================================================================
// Fused level kernel, R17: emb K-segment replaced by per-id LUT added in
// the EPILOGUE (bias folded in; 32B-aligned stride-8 rows, coalesced L2
// reads). K-loop covers ONLY recurrent segments:
//   VAR0 (BU node): cat 512 (8 steps);  VAR1/3 (edges): h 256 (4 steps);
//   VAR2 (TD node): ph 256 + cat 512 (12 steps; leaf: 4).
// Staging/compute structure = R15 (2-phase dbuf, proven).
// Packed W k-offset for step kt is 256+kt (emb rows 0..255 skipped).
// =========================================================================
template<int VAR, int NG>
__global__ __launch_bounds__(256, 2) void fused_gemm(
    int R, int logM, int s,
    const int* __restrict__ ids,
    const float* __restrict__ lutG,       // [id][256][8], bias folded
    const u16* __restrict__ hsrc,         // seg1: he_b/hl_b/ph_b per VAR
    const u16* __restrict__ hsrc2,        // seg2: he_b (VAR2 NG6 only)
    const u16* __restrict__ Wth, int wstride,
    const float* __restrict__ cce,        // children c (VAR0 / VAR2 NG6)
    const float* __restrict__ cprev,      // c_lvl (VAR1,3) / pc (VAR2)
    float* __restrict__ c_out,
    u16* __restrict__ h_out,
    float* __restrict__ out)
{
  constexpr int K1 = (VAR == 0) ? 512 : 256;
  constexpr int K2 = (VAR == 2 && NG == 6) ? 512 : 0;
  constexpr int KTOT = K1 + K2;
  constexpr int NSTEP = KTOT / 64;

  __shared__ u16 As[2][128][64];       // 2 x 16 KB
  __shared__ u16 Bs[2][NG * 32][64];   // 2 x NG*4 KB

  // XCD-aware bx swizzle (T1)
  int bx = blockIdx.x;
  if ((gridDim.x & 7) == 0){
    int q = (int)gridDim.x >> 3;
    bx = (bx & 7) * q + (bx >> 3);
  }

  int tid = threadIdx.x, lane = tid & 63, w = tid >> 6;
  int wrow = w >> 1, whh = w & 1;
  int hh0 = blockIdx.y * 32;
  int M = 1 << logM;

  int lrow8 = lane >> 3;            // row within 8-group
  int gran  = lane & 7;             // dest 16B granule
  int swz = (gran ^ lrow8) * 8;     // XOR pre-swizzled source k-elem offset

  // ---- 32-bit element offsets against uniform bases ----
  u32 off1[4]; u32 off2[4];
  #pragma unroll
  for (int c = 0; c < 4; ++c){
    int gr = bx * 128 + c * 32 + w * 8 + lrow8;
    if (gr > R - 1) gr = R - 1;                // clamp (stores guarded)
    int b = gr >> logM, m = gr & (M - 1);
    int j = s + m;
    if constexpr (VAR == 0)
      off1[c] = (u32)(b * NN + 2 * j + 1) * (u32)NH + (u32)swz;            // children h
    else if constexpr (VAR == 3)
      off1[c] = (u32)(b * (M >> 1) + (m >> 1)) * (u32)NH + (u32)swz;       // parent h
    else
      off1[c] = (u32)gr * (u32)NH + (u32)swz;                               // level h / ph
    if constexpr (K2 > 0)
      off2[c] = (u32)(b * NN + 2 * j + 1) * (u32)NH + (u32)swz;            // children h
    else
      off2[c] = 0;
  }
  u32 offB = (u32)(hh0 + w * 8 + lrow8) * (u32)wstride + (u32)swz + 256u;  // skip emb rows

  // stage K-step kt into buffer buf
  auto stage = [&](int buf, int kt){
    #pragma unroll
    for (int c = 0; c < 4; ++c){
      const u16* ga;
      if (K2 > 0 && kt >= K1) ga = hsrc2 + off2[c] + (kt - K1);
      else                    ga = hsrc  + off1[c] + kt;
      gload16(ga, &As[buf][c * 32 + w * 8][0]);
    }
    #pragma unroll
    for (int g = 0; g < NG; ++g)
      gload16(Wth + offB + (u32)(g * 256) * (u32)wstride + kt,
              &Bs[buf][g * 32 + w * 8][0]);
  };

  f32x4 acc[NG][4];
  #pragma unroll
  for (int g = 0; g < NG; ++g)
    #pragma unroll
    for (int i = 0; i < 4; ++i) acc[g][i] = (f32x4)0.0f;

  stage(0, 0);
  __syncthreads();                 // buf0 ready (implicit vmcnt(0) drain)

  #pragma unroll
  for (int st = 0; st < NSTEP; ++st){
    const int cur = st & 1;
    if (st + 1 < NSTEP) stage(cur ^ 1, (st + 1) * 64);   // fly during compute

    #pragma unroll
    for (int kc = 0; kc < 2; ++kc){
      int g2 = ((kc * 4 + (lane >> 4)) ^ (lane & 7)) * 8;
      bf16x8 a[4];
      #pragma unroll
      for (int i = 0; i < 4; ++i)
        a[i] = *(const bf16x8*)&As[cur][wrow * 64 + i * 16 + (lane & 15)][g2];
      bf16x8 bf[NG];
      #pragma unroll
      for (int g = 0; g < NG; ++g)
        bf[g] = *(const bf16x8*)&Bs[cur][g * 32 + whh * 16 + (lane & 15)][g2];
      #pragma unroll
      for (int g = 0; g < NG; ++g)
        #pragma unroll
        for (int i = 0; i < 4; ++i)
          acc[g][i] = __builtin_amdgcn_mfma_f32_16x16x32_bf16(a[i], bf[g], acc[g][i], 0, 0, 0);
    }
    __syncthreads();               // all waves done reading buf[cur];
                                   // next-stage loads drained (had full compute to land)
  }

  // ---- epilogue: per-lane fp32 gate math; per-id LUT replaces bias ----
  int hhL = hh0 + whh * 16 + (lane & 15);

  #pragma unroll
  for (int i = 0; i < 4; ++i){
    #pragma unroll
    for (int r = 0; r < 4; ++r){
      int row = bx * 128 + wrow * 64 + i * 16 + ((lane >> 4) << 2) + r;
      if (row >= R) continue;
      int b = row >> logM, m = row & (M - 1);
      int j = s + m;
      const float* lp = lutG + ((size_t)ids[b * NN + j] * 256 + hhL) * 8;
      if constexpr (VAR == 0){
        float iv = sigf(acc[0][i][r] + lp[0]);
        float ov = sigf(acc[1][i][r] + lp[1]);
        float uv = tanh_fast(acc[2][i][r] + lp[2]);
        float c = iv * uv;
        float f0 = sigf(acc[3][i][r] + lp[3]);
        float f1 = sigf(acc[4 % NG][i][r] + lp[4]);
        c += f0 * cce[((size_t)(b * NN + 2 * j + 1)) * NH + hhL]
           + f1 * cce[((size_t)(b * NN + 2 * j + 2)) * NH + hhL];
        float h = ov * tanh_fast(c);
        c_out[(size_t)row * NH + hhL] = c;
        h_out[(size_t)row * NH + hhL] = f2bf(h);
        out[((size_t)(b * NN + j)) * OUTW + hhL] = h;
      } else if constexpr (VAR == 1){
        float iv = sigf(acc[0][i][r] + lp[0]);
        float fv = sigf(acc[1][i][r] + lp[1]);
        float gg = tanh_fast(acc[2][i][r] + lp[2]);
        float ov = sigf(acc[3 % NG][i][r] + lp[3]);
        float c2 = fv * cprev[(size_t)row * NH + hhL] + iv * gg;
        float h2 = ov * tanh_fast(c2);
        size_t di = ((size_t)(b * NN + j)) * NH + hhL;     // node-global
        h_out[di] = f2bf(h2);
        c_out[di] = c2;
      } else if constexpr (VAR == 2){
        float iv = sigf(acc[0][i][r] + lp[0]);
        float ov = sigf(acc[1][i][r] + lp[1]);
        float uv = tanh_fast(acc[2][i][r] + lp[2]);
        float fp = sigf(acc[3 % NG][i][r] + lp[3]);
        float c = iv * uv + fp * cprev[(size_t)row * NH + hhL];
        if constexpr (NG == 6){
          float f0 = sigf(acc[4 % NG][i][r] + lp[4]);
          float f1 = sigf(acc[5 % NG][i][r] + lp[5]);
          c += f0 * cce[((size_t)(b * NN + 2 * j + 1)) * NH + hhL]
             + f1 * cce[((size_t)(b * NN + 2 * j + 2)) * NH + hhL];
        }
        float h = ov * tanh_fast(c);
        c_out[(size_t)row * NH + hhL] = c;
        h_out[(size_t)row * NH + hhL] = f2bf(h);
        out[((size_t)(b * NN + j)) * OUTW + NH + hhL] = h;
      } else {
        float iv = sigf(acc[0][i][r] + lp[0]);
        float fv = sigf(acc[1][i][r] + lp[1]);
        float gg = tanh_fast(acc[2][i][r] + lp[2]);
        float ov = sigf(acc[3 % NG][i][r] + lp[3]);
        int par = b * (M >> 1) + (m >> 1);
        float c2 = fv * cprev[(size_t)par * NH + hhL] + iv * gg;
        float h2 = ov * tanh_fast(c2);
        h_out[(size_t)row * NH + hhL] = f2bf(h2);          // ph for next level
        c_out[(size_t)row * NH + hhL] = c2;                // pc
      }
    }
  }
}

// ---- LUT builders ----
// lut[id][hh][stride] += (tab[id][0:256] @ Wt[:,koff:+256]^T)[g*256+hh] (+bias)
__global__ void build_lut(int nids, int ncols, int stride, int koff,
                          const u16* __restrict__ tab,
                          const u16* __restrict__ Wt, int wstride,
                          const float* __restrict__ bias,
                          float* __restrict__ lut)
{
  int t = blockIdx.x * 256 + threadIdx.x;
  if (t >= nids * ncols) return;
  int id = t / ncols, n = t % ncols;
  const u16* e  = tab + id * 256;
  const u16* wv = Wt + (size_t)n * wstride + koff;
  float z = bias ? bias[n] : 0.0f;
  for (int k = 0; k < 256; k += 8){
    #pragma unroll
    for (int q = 0; q < 8; ++q)
      z += bf2f(e[k + q]) * bf2f(wv[k + q]);
  }
  int hh = n & 255, g = n >> 8;
  lut[((size_t)id * 256 + hh) * stride + g] = z;
}

__global__ void build_leaf(const float* __restrict__ lut64,
                           float* __restrict__ c64, float* __restrict__ h64f,
                           u16* __restrict__ h64b)
{
  int t = blockIdx.x * 256 + threadIdx.x;     // 64*256
  const float* lp = lut64 + (size_t)t * 3;
  float iv = sigf(lp[0]), ov = sigf(lp[1]), uv = tanh_fast(lp[2]);
  float c = iv * uv;
  float h = ov * tanh_fast(c);
  c64[t] = c; h64f[t] = h; h64b[t] = f2bf(h);
}

// BU leaf node: out only.
__global__ void leaf_gather(const int* __restrict__ node_ids,
                            const float* __restrict__ h64f,
                            float* __restrict__ out)
{
  int t = blockIdx.x * 256 + threadIdx.x;     // 32768 * 64 (4 cols each)
  int gr = t >> 6, q4 = (t & 63) << 2;
  int b = gr >> 11, m = gr & 2047;
  int j = 2047 + m;
  int id = node_ids[b * NN + j];
  float4 hv = *(const float4*)(h64f + id * 256 + q4);
  *(float4*)(out + ((size_t)(b * NN + j)) * OUTW + q4) = hv;
}

// BU leaf edge-LSTM collapsed: g = lutE[eid] + lutH[nid]; cp = c64[nid].
__global__ void leaf_edge(const int* __restrict__ node_ids,
                          const int* __restrict__ edge_ids,
                          const float* __restrict__ lutE,   // [128][256][8] (bias in)
                          const float* __restrict__ lutH,   // [64][256][8]
                          const float* __restrict__ c64,
                          u16* __restrict__ he_b, float* __restrict__ ce_all)
{
  int gr = blockIdx.x;                        // leaf row 0..32767
  int hh = threadIdx.x;
  int b = gr >> 11, m = gr & 2047;
  int j = 2047 + m;
  int nid = node_ids[b * NN + j];
  int eid = edge_ids[b * NN + j];
  const float* pe = lutE + ((size_t)eid * 256 + hh) * 8;
  const float* ph = lutH + ((size_t)nid * 256 + hh) * 8;
  float iv = sigf(pe[0] + ph[0]);             // gate order [i|f|g|o]
  float fv = sigf(pe[1] + ph[1]);
  float gg = tanh_fast(pe[2] + ph[2]);
  float ov = sigf(pe[3] + ph[3]);
  float cp = c64[nid * 256 + hh];
  float c2 = fv * cp + iv * gg;
  float h2 = ov * tanh_fast(c2);
  size_t di = ((size_t)(b * NN + j)) * NH + hh;
  he_b[di] = f2bf(h2);
  ce_all[di] = c2;
}

// ---- weight packing: Wt[n][k], single-plane bf16 (unchanged, proven) ----

__global__ void pack_bu_node_t(const float* __restrict__ Wioux, const float* __restrict__ Wiouh,
                               const float* __restrict__ Wfx, const float* __restrict__ Wfh,
                               const float* __restrict__ bioux, const float* __restrict__ bfx,
                               u16* __restrict__ Wth, float* __restrict__ bd)
{
  int tid = blockIdx.x*256 + threadIdx.x;
  if (tid < 768*1280){
    int n = tid / 768, k = tid % 768;
    float v;
    if (n < 768){
      v = (k < 256) ? Wioux[k*768 + n] : Wiouh[(k-256)*768 + n];
    } else {
      int kidx = (n < 1024) ? 0 : 1;
      int nn = n - 768 - kidx*256;
      v = (k < 256) ? Wfx[k*256 + nn] : Wfh[((size_t)kidx*512 + (k-256))*256 + nn];
    }
    Wth[tid] = f2bf(v);
  }
  if (tid < 1280) bd[tid] = (tid < 768) ? bioux[tid] : bfx[(tid-768) & 255];
}

__global__ void pack_edge_t(const float* __restrict__ Wih, const float* __restrict__ Whh,
                            const float* __restrict__ bih, const float* __restrict__ bhh,
                            u16* __restrict__ Wth, float* __restrict__ bd)
{
  int tid = blockIdx.x*256 + threadIdx.x;
  if (tid < 512*1024){
    int n = tid / 512, k = tid % 512;
    float v = (k < 256) ? Wih[k*1024 + n] : Whh[(k-256)*1024 + n];
    Wth[tid] = f2bf(v);
  }
  if (tid < 1024) bd[tid] = bih[tid] + bhh[tid];
}

// TD node: rows [x(256)|ph(256)|cat(512)] k-stride 1024;
// cols [iou(768)|fpar(256)|f0(256)|f1(256)]
__global__ void pack_td_node_t(const float* __restrict__ Wioux, const float* __restrict__ Wiouhc,
                               const float* __restrict__ Wiouhp, const float* __restrict__ Wfx,
                               const float* __restrict__ Wfchild, const float* __restrict__ Wfparent,
                               const float* __restrict__ bioux, const float* __restrict__ bfx,
                               u16* __restrict__ Wth, float* __restrict__ bd)
{
  int tid = blockIdx.x*256 + threadIdx.x;
  if (tid < 1024*1536){
    int n = tid / 1024, k = tid % 1024;
    float v;
    if (n < 768){
      v = (k < 256) ? Wioux[k*768 + n]
        : (k < 512) ? Wiouhp[(k-256)*768 + n]
                    : Wiouhc[(k-512)*768 + n];
    } else if (n < 1024){
      int nn = n - 768;   // fpar
      v = (k < 256) ? Wfx[k*256 + nn] : Wfparent[(size_t)(k-256)*256 + nn];
    } else {
      int kidx = (n < 1280) ? 0 : 1;
      int nn = n - 1024 - kidx*256;
      v = (k < 256) ? Wfx[k*256 + nn]
                    : Wfchild[((size_t)kidx*768 + (k-256))*256 + nn];
    }
    Wth[tid] = f2bf(v);
  }
  if (tid < 1536) bd[tid] = (tid < 768) ? bioux[tid] : bfx[(tid-768) & 255];
}

// Embeddings + TD-root state zeroing
__global__ void pack_emb(const float* __restrict__ ne, const float* __restrict__ ee,
                         u16* __restrict__ neb, u16* __restrict__ eeb,
                         u16* __restrict__ ph_b, float* __restrict__ pc)
{
  int tid = blockIdx.x*256 + threadIdx.x;
  if (tid < 64*256)  neb[tid] = f2bf(ne[tid]);
  if (tid < 128*256) eeb[tid] = f2bf(ee[tid]);
  if (tid < NB*NH){ ph_b[tid] = 0; pc[tid] = 0.0f; }
}

extern "C" void kernel_launch(void* const* d_in, const int* in_sizes, int n_in,
                              void* d_out, int out_size, void* d_ws, size_t ws_size,
                              hipStream_t stream)
{
  const float* node_emb  = (const float*)d_in[0];
  const float* edge_emb  = (const float*)d_in[1];
  const float* bu_Wioux  = (const float*)d_in[2];
  const float* bu_bioux  = (const float*)d_in[3];
  const float* bu_Wfx    = (const float*)d_in[4];
  const float* bu_bfx    = (const float*)d_in[5];
  const float* bu_Wiouh  = (const float*)d_in[6];
  const float* bu_Wfh    = (const float*)d_in[7];
  const float* bu_eWih   = (const float*)d_in[8];
  const float* bu_eWhh   = (const float*)d_in[9];
  const float* bu_ebih   = (const float*)d_in[10];
  const float* bu_ebhh   = (const float*)d_in[11];
  const float* td_Wioux  = (const float*)d_in[12];
  const float* td_bioux  = (const float*)d_in[13];
  const float* td_Wfx    = (const float*)d_in[14];
  const float* td_bfx    = (const float*)d_in[15];
  const float* td_Wiouhc = (const float*)d_in[16];
  const float* td_Wiouhp = (const float*)d_in[17];
  const float* td_Wfchild= (const float*)d_in[18];
  const float* td_Wfparent=(const float*)d_in[19];
  const float* td_eWih   = (const float*)d_in[20];
  const float* td_eWhh   = (const float*)d_in[21];
  const float* td_ebih   = (const float*)d_in[22];
  const float* td_ebhh   = (const float*)d_in[23];
  const int* node_ids    = (const int*)d_in[24];
  const int* edge_ids    = (const int*)d_in[25];
  float* out = (float*)d_out;

  // ---- workspace ----
  float* fw = (float*)d_ws;
  size_t fo = 0;
  float* bbun = fw + fo; fo += 1280;
  float* bbue = fw + fo; fo += 1024;
  float* btdn = fw + fo; fo += 1536;
  float* btde = fw + fo; fo += 1024;
  float* lut64 = fw + fo; fo += (size_t)64*256*3;
  float* c64  = fw + fo; fo += (size_t)64*256;
  float* h64f = fw + fo; fo += (size_t)64*256;
  float* lutBUN = fw + fo; fo += (size_t)64*256*8;
  float* lutTDN = fw + fo; fo += (size_t)64*256*8;
  float* lutBUE = fw + fo; fo += (size_t)128*256*8;
  float* lutTDE = fw + fo; fo += (size_t)128*256*8;
  float* lutH   = fw + fo; fo += (size_t)64*256*8;
  float* ce_all = fw + fo; fo += (size_t)NB*NN*NH;
  float* c_lvl  = fw + fo; fo += (size_t)NB*2048*NH;
  float* pc     = fw + fo; fo += (size_t)NB*2048*NH;

  u16* uw = (u16*)(fw + fo);
  size_t uo = 0;
  u16* Wbunh = uw + uo; uo += (size_t)768*1280;
  u16* Wbueh = uw + uo; uo += (size_t)512*1024;
  u16* Wtdnh = uw + uo; uo += (size_t)1024*1536;
  u16* Wtdeh = uw + uo; uo += (size_t)512*1024;
  u16* neb = uw + uo; uo += (size_t)64*256;
  u16* eeb = uw + uo; uo += (size_t)128*256;
  u16* h64b = uw + uo; uo += (size_t)64*256;
  u16* he_b = uw + uo; uo += (size_t)NB*NN*NH;
  u16* hl_b = uw + uo; uo += (size_t)NB*2048*NH;
  u16* ph_b = uw + uo; uo += (size_t)NB*2048*NH;

  // ---- pack ----
  pack_bu_node_t<<<(768*1280+255)/256, 256, 0, stream>>>(bu_Wioux, bu_Wiouh, bu_Wfx, bu_Wfh,
      bu_bioux, bu_bfx, Wbunh, bbun);
  pack_edge_t<<<(512*1024+255)/256, 256, 0, stream>>>(bu_eWih, bu_eWhh, bu_ebih, bu_ebhh,
      Wbueh, bbue);
  pack_td_node_t<<<(1024*1536+255)/256, 256, 0, stream>>>(td_Wioux, td_Wiouhc, td_Wiouhp, td_Wfx,
      td_Wfchild, td_Wfparent, td_bioux, td_bfx, Wtdnh, btdn);
  pack_edge_t<<<(512*1024+255)/256, 256, 0, stream>>>(td_eWih, td_eWhh, td_ebih, td_ebhh,
      Wtdeh, btde);
  pack_emb<<<(128*256+255)/256, 256, 0, stream>>>(node_emb, edge_emb, neb, eeb, ph_b, pc);

  // ---- id LUTs (emb @ W + bias), stride-8 padded rows ----
  build_lut<<<(64*768+255)/256, 256, 0, stream>>>(64, 768, 3, 0, neb, Wbunh, 768, bbun, lut64);
  build_leaf<<<64, 256, 0, stream>>>(lut64, c64, h64f, h64b);
  build_lut<<<(64*1280+255)/256, 256, 0, stream>>>(64, 1280, 8, 0, neb, Wbunh, 768, bbun, lutBUN);
  build_lut<<<(64*1536+255)/256, 256, 0, stream>>>(64, 1536, 8, 0, neb, Wtdnh, 1024, btdn, lutTDN);
  build_lut<<<(128*1024+255)/256, 256, 0, stream>>>(128, 1024, 8, 0, eeb, Wbueh, 512, bbue, lutBUE);
  build_lut<<<(128*1024+255)/256, 256, 0, stream>>>(128, 1024, 8, 0, eeb, Wtdeh, 512, btde, lutTDE);
  build_lut<<<(64*1024+255)/256, 256, 0, stream>>>(64, 1024, 8, 256, h64b, Wbueh, 512, nullptr, lutH);

  // ---------- bottom-up ----------
  {   // leaf level l=11: node = gather; edge = collapsed table-lookup LSTM
    int R = NB * 2048;
    leaf_gather<<<(R * 64) / 256, 256, 0, stream>>>(node_ids, h64f, out);
    leaf_edge<<<R, 256, 0, stream>>>(node_ids, edge_ids, lutBUE, lutH, c64, he_b, ce_all);
  }
  for (int l = NLV-2; l >= 0; --l){
    int M = 1<<l, s = M-1, R = NB*M;
    dim3 grid((R + 127) / 128, NH / 32);
    fused_gemm<0,5><<<grid, 256, 0, stream>>>(R, l, s, node_ids,
        lutBUN, he_b, nullptr, Wbunh, 768,
        ce_all, nullptr, c_lvl, hl_b, out);
    if (l > 0){   // BU l=0 edge-LSTM output is never consumed -> skip
      fused_gemm<1,4><<<grid, 256, 0, stream>>>(R, l, s, edge_ids,
          lutBUE, hl_b, nullptr, Wbueh, 512,
          nullptr, c_lvl, ce_all, he_b, nullptr);
    }
  }

  // ---------- top-down ----------
  for (int l = 0; l < NLV; ++l){
    int M = 1<<l, s = M-1, R = NB*M;
    bool leaf = (l == NLV-1);
    dim3 grid((R + 127) / 128, NH / 32);
    if (!leaf){
      fused_gemm<2,6><<<grid, 256, 0, stream>>>(R, l, s, node_ids,
          lutTDN, ph_b, he_b, Wtdnh, 1024,
          ce_all, pc, c_lvl, hl_b, out);
      int M2 = 2*M, s2 = 2*M-1, R2 = NB*M2;
      dim3 grid2((R2 + 127) / 128, NH / 32);
      fused_gemm<3,4><<<grid2, 256, 0, stream>>>(R2, l+1, s2, edge_ids,
          lutTDE, hl_b, nullptr, Wtdeh, 512,
          nullptr, c_lvl, pc, ph_b, nullptr);
    } else {
      fused_gemm<2,4><<<grid, 256, 0, stream>>>(R, l, s, node_ids,
          lutTDN, ph_b, nullptr, Wtdnh, 1024,
          nullptr, pc, c_lvl, hl_b, out);
    }
  }
}

// Round 18
// 1111.114 us; speedup vs baseline: 1.0363x; 1.0363x over previous
//
#include <hip/hip_runtime.h>
#include <math.h>

#define NB 16       // batch
#define NH 256      // hidden dim
#define NLV 12      // levels
#define NN 4095     // nodes
#define OUTW 512    // output last-dim (2H)

typedef unsigned short u16;
typedef unsigned int u32;
typedef __attribute__((ext_vector_type(4))) float f32x4;
typedef __attribute__((ext_vector_type(8))) short bf16x8;

// Fast gate math: v_exp_f32 + v_rcp_f32 (limits exact, no NaN paths).
__device__ __forceinline__ float sigf(float x){
  return __fdividef(1.0f, 1.0f + __expf(-x));
}
__device__ __forceinline__ float tanh_fast(float x){
  return 1.0f - __fdividef(2.0f, 1.0f + __expf(2.0f * x));
}

__device__ __forceinline__ u16 f2bf(float x){
  unsigned int u = __float_as_uint(x);
  return (u16)((u + 0x7fffu + ((u >> 16) & 1u)) >> 16);
}
__device__ __forceinline__ float bf2f(u16 h){
  return __uint_as_float(((unsigned int)h) << 16);
}

// async global->LDS, 16B per lane; LDS dest = wave-uniform base + lane*16
__device__ __forceinline__ void gload16(const void* g, void* l){
  __builtin_amdgcn_global_load_lds(
      (const __attribute__((address_space(1))) unsigned int*)g,
      (__attribute__((address_space(3))) unsigned int*)l, 16, 0, 0);
}

// =========================================================================
// Fused level kernel (R16-proven: emb in K0, 2-phase dbuf staging).
// VAR: 0 = BU node, 1 = BU edge-LSTM, 2 = TD node, 3 = TD edge-LSTM.
// Tile: 128 rows x 32 hh x NG gates. 256 thr = 4 waves (2 row x 2 hh).
// =========================================================================
template<int VAR, int NG>
__global__ __launch_bounds__(256, 2) void fused_gemm(
    int R, int logM, int s,
    const int* __restrict__ ids,
    const u16* __restrict__ emb,          // seg0: embedding table
    const u16* __restrict__ hsrc,         // seg1: he_b/hl_b/ph_b per VAR
    const u16* __restrict__ hsrc2,        // seg2: he_b (VAR2 NG6 only)
    const u16* __restrict__ Wth, int wstride,
    const float* __restrict__ bias,
    const float* __restrict__ cce,        // children c (VAR0 / VAR2 NG6)
    const float* __restrict__ cprev,      // c_lvl (VAR1,3) / pc (VAR2)
    float* __restrict__ c_out,
    u16* __restrict__ h_out,
    float* __restrict__ out)
{
  constexpr int K0 = 256;
  constexpr int K1 = (VAR == 0) ? 512 : 256;
  constexpr int K2 = (VAR == 2 && NG == 6) ? 512 : 0;
  constexpr int KTOT = K0 + K1 + K2;
  constexpr int NSTEP = KTOT / 64;

  __shared__ u16 As[2][128][64];       // 2 x 16 KB
  __shared__ u16 Bs[2][NG * 32][64];   // 2 x NG*4 KB

  // XCD-aware bx swizzle (T1)
  int bx = blockIdx.x;
  if ((gridDim.x & 7) == 0){
    int q = (int)gridDim.x >> 3;
    bx = (bx & 7) * q + (bx >> 3);
  }

  int tid = threadIdx.x, lane = tid & 63, w = tid >> 6;
  int wrow = w >> 1, whh = w & 1;
  int hh0 = blockIdx.y * 32;
  int M = 1 << logM;

  int lrow8 = lane >> 3;            // row within 8-group
  int gran  = lane & 7;             // dest 16B granule
  int swz = (gran ^ lrow8) * 8;     // XOR pre-swizzled source k-elem offset

  // ---- 32-bit element offsets against uniform bases (R13-proven) ----
  u32 off0[4]; u32 off1[4]; u32 off2[4];
  #pragma unroll
  for (int c = 0; c < 4; ++c){
    int gr = bx * 128 + c * 32 + w * 8 + lrow8;
    if (gr > R - 1) gr = R - 1;                // clamp (stores guarded)
    int b = gr >> logM, m = gr & (M - 1);
    int j = s + m;
    off0[c] = (u32)ids[b * NN + j] * 256u + (u32)swz;
    if constexpr (VAR == 0)
      off1[c] = (u32)(b * NN + 2 * j + 1) * (u32)NH + (u32)swz;            // children h
    else if constexpr (VAR == 3)
      off1[c] = (u32)(b * (M >> 1) + (m >> 1)) * (u32)NH + (u32)swz;       // parent h
    else
      off1[c] = (u32)gr * (u32)NH + (u32)swz;                               // level h / ph
    if constexpr (K2 > 0)
      off2[c] = (u32)(b * NN + 2 * j + 1) * (u32)NH + (u32)swz;            // children h
    else
      off2[c] = 0;
  }
  u32 offB = (u32)(hh0 + w * 8 + lrow8) * (u32)wstride + (u32)swz;

  // stage K-step kt into buffer buf
  auto stage = [&](int buf, int kt){
    #pragma unroll
    for (int c = 0; c < 4; ++c){
      const u16* ga;
      if (kt < K0)               ga = emb   + off0[c] + kt;
      else if (kt < K0 + K1)     ga = hsrc  + off1[c] + (kt - K0);
      else                       ga = hsrc2 + off2[c] + (kt - K0 - K1);
      gload16(ga, &As[buf][c * 32 + w * 8][0]);
    }
    #pragma unroll
    for (int g = 0; g < NG; ++g)
      gload16(Wth + offB + (u32)(g * 256) * (u32)wstride + kt,
              &Bs[buf][g * 32 + w * 8][0]);
  };

  f32x4 acc[NG][4];
  #pragma unroll
  for (int g = 0; g < NG; ++g)
    #pragma unroll
    for (int i = 0; i < 4; ++i) acc[g][i] = (f32x4)0.0f;

  stage(0, 0);
  __syncthreads();                 // buf0 ready (implicit vmcnt(0) drain)

  #pragma unroll
  for (int st = 0; st < NSTEP; ++st){
    const int cur = st & 1;
    if (st + 1 < NSTEP) stage(cur ^ 1, (st + 1) * 64);   // fly during compute

    #pragma unroll
    for (int kc = 0; kc < 2; ++kc){
      int g2 = ((kc * 4 + (lane >> 4)) ^ (lane & 7)) * 8;
      bf16x8 a[4];
      #pragma unroll
      for (int i = 0; i < 4; ++i)
        a[i] = *(const bf16x8*)&As[cur][wrow * 64 + i * 16 + (lane & 15)][g2];
      bf16x8 bf[NG];
      #pragma unroll
      for (int g = 0; g < NG; ++g)
        bf[g] = *(const bf16x8*)&Bs[cur][g * 32 + whh * 16 + (lane & 15)][g2];
      #pragma unroll
      for (int g = 0; g < NG; ++g)
        #pragma unroll
        for (int i = 0; i < 4; ++i)
          acc[g][i] = __builtin_amdgcn_mfma_f32_16x16x32_bf16(a[i], bf[g], acc[g][i], 0, 0, 0);
    }
    __syncthreads();               // all waves done reading buf[cur];
                                   // next-stage loads drained (had full compute to land)
  }

  // ---- epilogue: per-lane fp32 gate math (native transcendentals) ----
  int hhL = hh0 + whh * 16 + (lane & 15);
  float bb[NG];
  #pragma unroll
  for (int g = 0; g < NG; ++g) bb[g] = bias[g * 256 + hhL];

  #pragma unroll
  for (int i = 0; i < 4; ++i){
    #pragma unroll
    for (int r = 0; r < 4; ++r){
      int row = bx * 128 + wrow * 64 + i * 16 + ((lane >> 4) << 2) + r;
      if (row >= R) continue;
      int b = row >> logM, m = row & (M - 1);
      int j = s + m;
      if constexpr (VAR == 0){
        float iv = sigf(acc[0][i][r] + bb[0]);
        float ov = sigf(acc[1][i][r] + bb[1]);
        float uv = tanh_fast(acc[2][i][r] + bb[2]);
        float c = iv * uv;
        float f0 = sigf(acc[3][i][r] + bb[3]);
        float f1 = sigf(acc[4 % NG][i][r] + bb[4 % NG]);
        c += f0 * cce[((size_t)(b * NN + 2 * j + 1)) * NH + hhL]
           + f1 * cce[((size_t)(b * NN + 2 * j + 2)) * NH + hhL];
        float h = ov * tanh_fast(c);
        c_out[(size_t)row * NH + hhL] = c;
        h_out[(size_t)row * NH + hhL] = f2bf(h);
        out[((size_t)(b * NN + j)) * OUTW + hhL] = h;
      } else if constexpr (VAR == 1){
        float iv = sigf(acc[0][i][r] + bb[0]);
        float fv = sigf(acc[1][i][r] + bb[1]);
        float gg = tanh_fast(acc[2][i][r] + bb[2]);
        float ov = sigf(acc[3 % NG][i][r] + bb[3 % NG]);
        float c2 = fv * cprev[(size_t)row * NH + hhL] + iv * gg;
        float h2 = ov * tanh_fast(c2);
        size_t di = ((size_t)(b * NN + j)) * NH + hhL;     // node-global
        h_out[di] = f2bf(h2);
        c_out[di] = c2;
      } else if constexpr (VAR == 2){
        float iv = sigf(acc[0][i][r] + bb[0]);
        float ov = sigf(acc[1][i][r] + bb[1]);
        float uv = tanh_fast(acc[2][i][r] + bb[2]);
        float fp = sigf(acc[3 % NG][i][r] + bb[3 % NG]);
        float c = iv * uv + fp * cprev[(size_t)row * NH + hhL];
        if constexpr (NG == 6){
          float f0 = sigf(acc[4 % NG][i][r] + bb[4 % NG]);
          float f1 = sigf(acc[5 % NG][i][r] + bb[5 % NG]);
          c += f0 * cce[((size_t)(b * NN + 2 * j + 1)) * NH + hhL]
             + f1 * cce[((size_t)(b * NN + 2 * j + 2)) * NH + hhL];
        }
        float h = ov * tanh_fast(c);
        c_out[(size_t)row * NH + hhL] = c;
        h_out[(size_t)row * NH + hhL] = f2bf(h);
        out[((size_t)(b * NN + j)) * OUTW + NH + hhL] = h;
      } else {
        float iv = sigf(acc[0][i][r] + bb[0]);
        float fv = sigf(acc[1][i][r] + bb[1]);
        float gg = tanh_fast(acc[2][i][r] + bb[2]);
        float ov = sigf(acc[3 % NG][i][r] + bb[3 % NG]);
        int par = b * (M >> 1) + (m >> 1);
        float c2 = fv * cprev[(size_t)par * NH + hhL] + iv * gg;
        float h2 = ov * tanh_fast(c2);
        h_out[(size_t)row * NH + hhL] = f2bf(h2);          // ph for next level
        c_out[(size_t)row * NH + hhL] = c2;                // pc
      }
    }
  }
}

// ---- mega-pack: all weight packs + emb + ph/pc zero in ONE kernel ----
__global__ void mega_pack(
    const float* __restrict__ bu_Wioux, const float* __restrict__ bu_Wiouh,
    const float* __restrict__ bu_Wfx, const float* __restrict__ bu_Wfh,
    const float* __restrict__ bu_bioux, const float* __restrict__ bu_bfx,
    const float* __restrict__ bu_eWih, const float* __restrict__ bu_eWhh,
    const float* __restrict__ bu_ebih, const float* __restrict__ bu_ebhh,
    const float* __restrict__ td_Wioux, const float* __restrict__ td_Wiouhc,
    const float* __restrict__ td_Wiouhp, const float* __restrict__ td_Wfx,
    const float* __restrict__ td_Wfchild, const float* __restrict__ td_Wfparent,
    const float* __restrict__ td_bioux, const float* __restrict__ td_bfx,
    const float* __restrict__ td_eWih, const float* __restrict__ td_eWhh,
    const float* __restrict__ td_ebih, const float* __restrict__ td_ebhh,
    const float* __restrict__ ne, const float* __restrict__ ee,
    u16* __restrict__ Wbunh, float* __restrict__ bbun,
    u16* __restrict__ Wbueh, float* __restrict__ bbue,
    u16* __restrict__ Wtdnh, float* __restrict__ btdn,
    u16* __restrict__ Wtdeh, float* __restrict__ btde,
    u16* __restrict__ neb, u16* __restrict__ eeb,
    u16* __restrict__ ph_b, float* __restrict__ pc)
{
  int tid = blockIdx.x*256 + threadIdx.x;
  // TD node: rows [x|ph|cat] k-stride 1024; cols [iou|fpar|f0|f1]
  if (tid < 1024*1536){
    int n = tid / 1024, k = tid % 1024;
    float v;
    if (n < 768){
      v = (k < 256) ? td_Wioux[k*768 + n]
        : (k < 512) ? td_Wiouhp[(k-256)*768 + n]
                    : td_Wiouhc[(k-512)*768 + n];
    } else if (n < 1024){
      int nn = n - 768;
      v = (k < 256) ? td_Wfx[k*256 + nn] : td_Wfparent[(size_t)(k-256)*256 + nn];
    } else {
      int kidx = (n < 1280) ? 0 : 1;
      int nn = n - 1024 - kidx*256;
      v = (k < 256) ? td_Wfx[k*256 + nn]
                    : td_Wfchild[((size_t)kidx*768 + (k-256))*256 + nn];
    }
    Wtdnh[tid] = f2bf(v);
  }
  // BU node: rows [x|cat] k-stride 768; cols [iou|f0|f1]
  if (tid < 768*1280){
    int n = tid / 768, k = tid % 768;
    float v;
    if (n < 768){
      v = (k < 256) ? bu_Wioux[k*768 + n] : bu_Wiouh[(k-256)*768 + n];
    } else {
      int kidx = (n < 1024) ? 0 : 1;
      int nn = n - 768 - kidx*256;
      v = (k < 256) ? bu_Wfx[k*256 + nn] : bu_Wfh[((size_t)kidx*512 + (k-256))*256 + nn];
    }
    Wbunh[tid] = f2bf(v);
  }
  // both edges: rows [x|h] k-stride 512
  if (tid < 512*1024){
    int n = tid / 512, k = tid % 512;
    float v1 = (k < 256) ? bu_eWih[k*1024 + n] : bu_eWhh[(k-256)*1024 + n];
    float v2 = (k < 256) ? td_eWih[k*1024 + n] : td_eWhh[(k-256)*1024 + n];
    Wbueh[tid] = f2bf(v1);
    Wtdeh[tid] = f2bf(v2);
  }
  // biases
  if (tid < 1536) btdn[tid] = (tid < 768) ? td_bioux[tid] : td_bfx[(tid-768) & 255];
  if (tid < 1280) bbun[tid] = (tid < 768) ? bu_bioux[tid] : bu_bfx[(tid-768) & 255];
  if (tid < 1024){
    bbue[tid] = bu_ebih[tid] + bu_ebhh[tid];
    btde[tid] = td_ebih[tid] + td_ebhh[tid];
  }
  // embeddings + TD-root zero
  if (tid < 64*256)  neb[tid] = f2bf(ne[tid]);
  if (tid < 128*256) eeb[tid] = f2bf(ee[tid]);
  if (tid < NB*NH){ ph_b[tid] = 0; pc[tid] = 0.0f; }
}

// ---- fused LUT build #1: lut64 (BU node iou over 64 ids) + lutE (edge x) ----
__global__ void build_luts1(const u16* __restrict__ neb, const u16* __restrict__ eeb,
                            const u16* __restrict__ Wbunh, const float* __restrict__ bbun,
                            const u16* __restrict__ Wbueh, const float* __restrict__ bbue,
                            float* __restrict__ lut64, float* __restrict__ lutE)
{
  int t = blockIdx.x * 256 + threadIdx.x;
  if (t < 64*768){
    int id = t / 768, n = t % 768;
    const u16* e  = neb + id * 256;
    const u16* wv = Wbunh + (size_t)n * 768;
    float z = bbun[n];
    for (int k = 0; k < 256; k += 8){
      #pragma unroll
      for (int q = 0; q < 8; ++q) z += bf2f(e[k + q]) * bf2f(wv[k + q]);
    }
    lut64[((size_t)id * 256 + (n & 255)) * 3 + (n >> 8)] = z;
  } else if (t < 64*768 + 128*1024){
    int tt = t - 64*768;
    int id = tt / 1024, n = tt % 1024;
    const u16* e  = eeb + id * 256;
    const u16* wv = Wbueh + (size_t)n * 512;
    float z = bbue[n];
    for (int k = 0; k < 256; k += 8){
      #pragma unroll
      for (int q = 0; q < 8; ++q) z += bf2f(e[k + q]) * bf2f(wv[k + q]);
    }
    lutE[((size_t)id * 256 + (n & 255)) * 4 + (n >> 8)] = z;
  }
}

__global__ void build_leaf(const float* __restrict__ lut64,
                           float* __restrict__ c64, float* __restrict__ h64f,
                           u16* __restrict__ h64b)
{
  int t = blockIdx.x * 256 + threadIdx.x;     // 64*256
  const float* lp = lut64 + (size_t)t * 3;
  float iv = sigf(lp[0]), ov = sigf(lp[1]), uv = tanh_fast(lp[2]);
  float c = iv * uv;
  float h = ov * tanh_fast(c);
  c64[t] = c; h64f[t] = h; h64b[t] = f2bf(h);
}

// lutH[id][hh][4] = h_leaf[id] @ Whh (k-offset 256, no bias)
__global__ void build_lutH(const u16* __restrict__ h64b,
                           const u16* __restrict__ Wbueh,
                           float* __restrict__ lutH)
{
  int t = blockIdx.x * 256 + threadIdx.x;     // 64*1024
  int id = t / 1024, n = t % 1024;
  const u16* e  = h64b + id * 256;
  const u16* wv = Wbueh + (size_t)n * 512 + 256;
  float z = 0.0f;
  for (int k = 0; k < 256; k += 8){
    #pragma unroll
    for (int q = 0; q < 8; ++q) z += bf2f(e[k + q]) * bf2f(wv[k + q]);
  }
  lutH[((size_t)id * 256 + (n & 255)) * 4 + (n >> 8)] = z;
}

// BU leaf: node-out gather + collapsed edge-LSTM in ONE kernel.
__global__ void leaf_edge(const int* __restrict__ node_ids,
                          const int* __restrict__ edge_ids,
                          const float* __restrict__ lutE,   // [128][256][4] (bias in)
                          const float* __restrict__ lutH,   // [64][256][4]
                          const float* __restrict__ c64,
                          const float* __restrict__ h64f,
                          u16* __restrict__ he_b, float* __restrict__ ce_all,
                          float* __restrict__ out)
{
  int gr = blockIdx.x;                        // leaf row 0..32767
  int hh = threadIdx.x;
  int b = gr >> 11, m = gr & 2047;
  int j = 2047 + m;
  int nid = node_ids[b * NN + j];
  int eid = edge_ids[b * NN + j];
  // node out (was leaf_gather)
  out[((size_t)(b * NN + j)) * OUTW + hh] = h64f[nid * 256 + hh];
  // collapsed edge-LSTM
  float4 ge = *(const float4*)(lutE + ((size_t)eid * 256 + hh) * 4);
  float4 gh = *(const float4*)(lutH + ((size_t)nid * 256 + hh) * 4);
  float iv = sigf(ge.x + gh.x);               // gate order [i|f|g|o]
  float fv = sigf(ge.y + gh.y);
  float gg = tanh_fast(ge.z + gh.z);
  float ov = sigf(ge.w + gh.w);
  float cp = c64[nid * 256 + hh];
  float c2 = fv * cp + iv * gg;
  float h2 = ov * tanh_fast(c2);
  size_t di = ((size_t)(b * NN + j)) * NH + hh;
  he_b[di] = f2bf(h2);
  ce_all[di] = c2;
}

extern "C" void kernel_launch(void* const* d_in, const int* in_sizes, int n_in,
                              void* d_out, int out_size, void* d_ws, size_t ws_size,
                              hipStream_t stream)
{
  const float* node_emb  = (const float*)d_in[0];
  const float* edge_emb  = (const float*)d_in[1];
  const float* bu_Wioux  = (const float*)d_in[2];
  const float* bu_bioux  = (const float*)d_in[3];
  const float* bu_Wfx    = (const float*)d_in[4];
  const float* bu_bfx    = (const float*)d_in[5];
  const float* bu_Wiouh  = (const float*)d_in[6];
  const float* bu_Wfh    = (const float*)d_in[7];
  const float* bu_eWih   = (const float*)d_in[8];
  const float* bu_eWhh   = (const float*)d_in[9];
  const float* bu_ebih   = (const float*)d_in[10];
  const float* bu_ebhh   = (const float*)d_in[11];
  const float* td_Wioux  = (const float*)d_in[12];
  const float* td_bioux  = (const float*)d_in[13];
  const float* td_Wfx    = (const float*)d_in[14];
  const float* td_bfx    = (const float*)d_in[15];
  const float* td_Wiouhc = (const float*)d_in[16];
  const float* td_Wiouhp = (const float*)d_in[17];
  const float* td_Wfchild= (const float*)d_in[18];
  const float* td_Wfparent=(const float*)d_in[19];
  const float* td_eWih   = (const float*)d_in[20];
  const float* td_eWhh   = (const float*)d_in[21];
  const float* td_ebih   = (const float*)d_in[22];
  const float* td_ebhh   = (const float*)d_in[23];
  const int* node_ids    = (const int*)d_in[24];
  const int* edge_ids    = (const int*)d_in[25];
  float* out = (float*)d_out;

  // ---- workspace ----
  float* fw = (float*)d_ws;
  size_t fo = 0;
  float* bbun = fw + fo; fo += 1280;
  float* bbue = fw + fo; fo += 1024;
  float* btdn = fw + fo; fo += 1536;
  float* btde = fw + fo; fo += 1024;
  float* lut64 = fw + fo; fo += (size_t)64*256*3;
  float* c64  = fw + fo; fo += (size_t)64*256;
  float* h64f = fw + fo; fo += (size_t)64*256;
  float* lutE = fw + fo; fo += (size_t)128*256*4;
  float* lutH = fw + fo; fo += (size_t)64*256*4;
  float* ce_all = fw + fo; fo += (size_t)NB*NN*NH;
  float* c_lvl  = fw + fo; fo += (size_t)NB*2048*NH;
  float* pc     = fw + fo; fo += (size_t)NB*2048*NH;

  u16* uw = (u16*)(fw + fo);
  size_t uo = 0;
  u16* Wbunh = uw + uo; uo += (size_t)768*1280;
  u16* Wbueh = uw + uo; uo += (size_t)512*1024;
  u16* Wtdnh = uw + uo; uo += (size_t)1024*1536;
  u16* Wtdeh = uw + uo; uo += (size_t)512*1024;
  u16* neb = uw + uo; uo += (size_t)64*256;
  u16* eeb = uw + uo; uo += (size_t)128*256;
  u16* h64b = uw + uo; uo += (size_t)64*256;
  u16* he_b = uw + uo; uo += (size_t)NB*NN*NH;
  u16* hl_b = uw + uo; uo += (size_t)NB*2048*NH;
  u16* ph_b = uw + uo; uo += (size_t)NB*2048*NH;

  // ---- pack (1 launch) ----
  mega_pack<<<(1024*1536+255)/256, 256, 0, stream>>>(
      bu_Wioux, bu_Wiouh, bu_Wfx, bu_Wfh, bu_bioux, bu_bfx,
      bu_eWih, bu_eWhh, bu_ebih, bu_ebhh,
      td_Wioux, td_Wiouhc, td_Wiouhp, td_Wfx, td_Wfchild, td_Wfparent,
      td_bioux, td_bfx, td_eWih, td_eWhh, td_ebih, td_ebhh,
      node_emb, edge_emb,
      Wbunh, bbun, Wbueh, bbue, Wtdnh, btdn, Wtdeh, btde,
      neb, eeb, ph_b, pc);

  // ---- BU leaf tables (3 launches) ----
  build_luts1<<<(64*768 + 128*1024 + 255)/256, 256, 0, stream>>>(
      neb, eeb, Wbunh, bbun, Wbueh, bbue, lut64, lutE);
  build_leaf<<<64, 256, 0, stream>>>(lut64, c64, h64f, h64b);
  build_lutH<<<(64*1024)/256, 256, 0, stream>>>(h64b, Wbueh, lutH);

  // ---------- bottom-up ----------
  {   // leaf level l=11: node gather + collapsed edge-LSTM, one kernel
    int R = NB * 2048;
    leaf_edge<<<R, 256, 0, stream>>>(node_ids, edge_ids, lutE, lutH, c64, h64f,
        he_b, ce_all, out);
  }
  for (int l = NLV-2; l >= 0; --l){
    int M = 1<<l, s = M-1, R = NB*M;
    dim3 grid((R + 127) / 128, NH / 32);
    fused_gemm<0,5><<<grid, 256, 0, stream>>>(R, l, s, node_ids,
        neb, he_b, neb, Wbunh, 768, bbun,
        ce_all, nullptr, c_lvl, hl_b, out);
    if (l > 0){   // BU l=0 edge-LSTM output is never consumed -> skip
      fused_gemm<1,4><<<grid, 256, 0, stream>>>(R, l, s, edge_ids,
          eeb, hl_b, neb, Wbueh, 512, bbue,
          nullptr, c_lvl, ce_all, he_b, nullptr);
    }
  }

  // ---------- top-down ----------
  for (int l = 0; l < NLV; ++l){
    int M = 1<<l, s = M-1, R = NB*M;
    bool leaf = (l == NLV-1);
    dim3 grid((R + 127) / 128, NH / 32);
    if (!leaf){
      fused_gemm<2,6><<<grid, 256, 0, stream>>>(R, l, s, node_ids,
          neb, ph_b, he_b, Wtdnh, 1024, btdn,
          ce_all, pc, c_lvl, hl_b, out);
      int M2 = 2*M, s2 = 2*M-1, R2 = NB*M2;
      dim3 grid2((R2 + 127) / 128, NH / 32);
      fused_gemm<3,4><<<grid2, 256, 0, stream>>>(R2, l+1, s2, edge_ids,
          eeb, hl_b, neb, Wtdeh, 512, btde,
          nullptr, c_lvl, pc, ph_b, nullptr);
    } else {
      fused_gemm<2,4><<<grid, 256, 0, stream>>>(R, l, s, node_ids,
          neb, ph_b, neb, Wtdnh, 1024, btdn,
          nullptr, pc, c_lvl, hl_b, out);
    }
  }
}

// Round 19
// 1109.059 us; speedup vs baseline: 1.0382x; 1.0019x over previous
//
#include <hip/hip_runtime.h>
#include <math.h>

#define NB 16       // batch
#define NH 256      // hidden dim
#define NLV 12      // levels
#define NN 4095     // nodes
#define OUTW 512    // output last-dim (2H)

typedef unsigned short u16;
typedef unsigned int u32;
typedef __attribute__((ext_vector_type(4))) float f32x4;
typedef __attribute__((ext_vector_type(8))) short bf16x8;

// Fast gate math: v_exp_f32 + v_rcp_f32 (limits exact, no NaN paths).
__device__ __forceinline__ float sigf(float x){
  return __fdividef(1.0f, 1.0f + __expf(-x));
}
__device__ __forceinline__ float tanh_fast(float x){
  return 1.0f - __fdividef(2.0f, 1.0f + __expf(2.0f * x));
}

__device__ __forceinline__ u16 f2bf(float x){
  unsigned int u = __float_as_uint(x);
  return (u16)((u + 0x7fffu + ((u >> 16) & 1u)) >> 16);
}
__device__ __forceinline__ float bf2f(u16 h){
  return __uint_as_float(((unsigned int)h) << 16);
}

// async global->LDS, 16B per lane; LDS dest = wave-uniform base + lane*16
__device__ __forceinline__ void gload16(const void* g, void* l){
  __builtin_amdgcn_global_load_lds(
      (const __attribute__((address_space(1))) unsigned int*)g,
      (__attribute__((address_space(3))) unsigned int*)l, 16, 0, 0);
}

// =========================================================================
// Fused level kernel (R16/R18-proven: emb in K0, 2-phase dbuf staging).
// VAR: 0 = BU node, 1 = BU edge-LSTM, 2 = TD node, 3 = TD edge-LSTM.
// WS : write h/c state buffers (false where provably dead: TD leaf node,
//      BU l=0 node — overwritten before any read).
// Tile: 128 rows x 32 hh x NG gates. 256 thr = 4 waves (2 row x 2 hh).
// =========================================================================
template<int VAR, int NG, bool WS = true>
__global__ __launch_bounds__(256, 2) void fused_gemm(
    int R, int logM, int s,
    const int* __restrict__ ids,
    const u16* __restrict__ emb,          // seg0: embedding table
    const u16* __restrict__ hsrc,         // seg1: he_b/hl_b/ph_b per VAR
    const u16* __restrict__ hsrc2,        // seg2: he_b (VAR2 NG6 only)
    const u16* __restrict__ Wth, int wstride,
    const float* __restrict__ bias,
    const float* __restrict__ cce,        // children c (VAR0 / VAR2 NG6)
    const float* __restrict__ cprev,      // c_lvl (VAR1,3) / pc (VAR2)
    float* __restrict__ c_out,
    u16* __restrict__ h_out,
    float* __restrict__ out)
{
  constexpr int K0 = 256;
  constexpr int K1 = (VAR == 0) ? 512 : 256;
  constexpr int K2 = (VAR == 2 && NG == 6) ? 512 : 0;
  constexpr int KTOT = K0 + K1 + K2;
  constexpr int NSTEP = KTOT / 64;

  __shared__ u16 As[2][128][64];       // 2 x 16 KB
  __shared__ u16 Bs[2][NG * 32][64];   // 2 x NG*4 KB

  // XCD-aware bx swizzle (T1)
  int bx = blockIdx.x;
  if ((gridDim.x & 7) == 0){
    int q = (int)gridDim.x >> 3;
    bx = (bx & 7) * q + (bx >> 3);
  }

  int tid = threadIdx.x, lane = tid & 63, w = tid >> 6;
  int wrow = w >> 1, whh = w & 1;
  int hh0 = blockIdx.y * 32;
  int M = 1 << logM;

  int lrow8 = lane >> 3;            // row within 8-group
  int gran  = lane & 7;             // dest 16B granule
  int swz = (gran ^ lrow8) * 8;     // XOR pre-swizzled source k-elem offset

  // ---- 32-bit element offsets against uniform bases (R13-proven) ----
  u32 off0[4]; u32 off1[4]; u32 off2[4];
  #pragma unroll
  for (int c = 0; c < 4; ++c){
    int gr = bx * 128 + c * 32 + w * 8 + lrow8;
    if (gr > R - 1) gr = R - 1;                // clamp (stores guarded)
    int b = gr >> logM, m = gr & (M - 1);
    int j = s + m;
    off0[c] = (u32)ids[b * NN + j] * 256u + (u32)swz;
    if constexpr (VAR == 0)
      off1[c] = (u32)(b * NN + 2 * j + 1) * (u32)NH + (u32)swz;            // children h
    else if constexpr (VAR == 3)
      off1[c] = (u32)(b * (M >> 1) + (m >> 1)) * (u32)NH + (u32)swz;       // parent h
    else
      off1[c] = (u32)gr * (u32)NH + (u32)swz;                               // level h / ph
    if constexpr (K2 > 0)
      off2[c] = (u32)(b * NN + 2 * j + 1) * (u32)NH + (u32)swz;            // children h
    else
      off2[c] = 0;
  }
  u32 offB = (u32)(hh0 + w * 8 + lrow8) * (u32)wstride + (u32)swz;

  // stage K-step kt into buffer buf
  auto stage = [&](int buf, int kt){
    #pragma unroll
    for (int c = 0; c < 4; ++c){
      const u16* ga;
      if (kt < K0)               ga = emb   + off0[c] + kt;
      else if (kt < K0 + K1)     ga = hsrc  + off1[c] + (kt - K0);
      else                       ga = hsrc2 + off2[c] + (kt - K0 - K1);
      gload16(ga, &As[buf][c * 32 + w * 8][0]);
    }
    #pragma unroll
    for (int g = 0; g < NG; ++g)
      gload16(Wth + offB + (u32)(g * 256) * (u32)wstride + kt,
              &Bs[buf][g * 32 + w * 8][0]);
  };

  f32x4 acc[NG][4];
  #pragma unroll
  for (int g = 0; g < NG; ++g)
    #pragma unroll
    for (int i = 0; i < 4; ++i) acc[g][i] = (f32x4)0.0f;

  stage(0, 0);
  __syncthreads();                 // buf0 ready (implicit vmcnt(0) drain)

  #pragma unroll
  for (int st = 0; st < NSTEP; ++st){
    const int cur = st & 1;
    if (st + 1 < NSTEP) stage(cur ^ 1, (st + 1) * 64);   // fly during compute

    #pragma unroll
    for (int kc = 0; kc < 2; ++kc){
      int g2 = ((kc * 4 + (lane >> 4)) ^ (lane & 7)) * 8;
      bf16x8 a[4];
      #pragma unroll
      for (int i = 0; i < 4; ++i)
        a[i] = *(const bf16x8*)&As[cur][wrow * 64 + i * 16 + (lane & 15)][g2];
      bf16x8 bf[NG];
      #pragma unroll
      for (int g = 0; g < NG; ++g)
        bf[g] = *(const bf16x8*)&Bs[cur][g * 32 + whh * 16 + (lane & 15)][g2];
      #pragma unroll
      for (int g = 0; g < NG; ++g)
        #pragma unroll
        for (int i = 0; i < 4; ++i)
          acc[g][i] = __builtin_amdgcn_mfma_f32_16x16x32_bf16(a[i], bf[g], acc[g][i], 0, 0, 0);
    }
    __syncthreads();               // all waves done reading buf[cur];
                                   // next-stage loads drained (had full compute to land)
  }

  // ---- epilogue: per-lane fp32 gate math (native transcendentals) ----
  int hhL = hh0 + whh * 16 + (lane & 15);
  float bb[NG];
  #pragma unroll
  for (int g = 0; g < NG; ++g) bb[g] = bias[g * 256 + hhL];

  #pragma unroll
  for (int i = 0; i < 4; ++i){
    #pragma unroll
    for (int r = 0; r < 4; ++r){
      int row = bx * 128 + wrow * 64 + i * 16 + ((lane >> 4) << 2) + r;
      if (row >= R) continue;
      int b = row >> logM, m = row & (M - 1);
      int j = s + m;
      if constexpr (VAR == 0){
        float iv = sigf(acc[0][i][r] + bb[0]);
        float ov = sigf(acc[1][i][r] + bb[1]);
        float uv = tanh_fast(acc[2][i][r] + bb[2]);
        float c = iv * uv;
        float f0 = sigf(acc[3][i][r] + bb[3]);
        float f1 = sigf(acc[4 % NG][i][r] + bb[4 % NG]);
        c += f0 * cce[((size_t)(b * NN + 2 * j + 1)) * NH + hhL]
           + f1 * cce[((size_t)(b * NN + 2 * j + 2)) * NH + hhL];
        float h = ov * tanh_fast(c);
        if constexpr (WS){
          c_out[(size_t)row * NH + hhL] = c;
          h_out[(size_t)row * NH + hhL] = f2bf(h);
        }
        out[((size_t)(b * NN + j)) * OUTW + hhL] = h;
      } else if constexpr (VAR == 1){
        float iv = sigf(acc[0][i][r] + bb[0]);
        float fv = sigf(acc[1][i][r] + bb[1]);
        float gg = tanh_fast(acc[2][i][r] + bb[2]);
        float ov = sigf(acc[3 % NG][i][r] + bb[3 % NG]);
        float c2 = fv * cprev[(size_t)row * NH + hhL] + iv * gg;
        float h2 = ov * tanh_fast(c2);
        size_t di = ((size_t)(b * NN + j)) * NH + hhL;     // node-global
        h_out[di] = f2bf(h2);
        c_out[di] = c2;
      } else if constexpr (VAR == 2){
        float iv = sigf(acc[0][i][r] + bb[0]);
        float ov = sigf(acc[1][i][r] + bb[1]);
        float uv = tanh_fast(acc[2][i][r] + bb[2]);
        float fp = sigf(acc[3 % NG][i][r] + bb[3 % NG]);
        float c = iv * uv + fp * cprev[(size_t)row * NH + hhL];
        if constexpr (NG == 6){
          float f0 = sigf(acc[4 % NG][i][r] + bb[4 % NG]);
          float f1 = sigf(acc[5 % NG][i][r] + bb[5 % NG]);
          c += f0 * cce[((size_t)(b * NN + 2 * j + 1)) * NH + hhL]
             + f1 * cce[((size_t)(b * NN + 2 * j + 2)) * NH + hhL];
        }
        float h = ov * tanh_fast(c);
        if constexpr (WS){
          c_out[(size_t)row * NH + hhL] = c;
          h_out[(size_t)row * NH + hhL] = f2bf(h);
        }
        out[((size_t)(b * NN + j)) * OUTW + NH + hhL] = h;
      } else {
        float iv = sigf(acc[0][i][r] + bb[0]);
        float fv = sigf(acc[1][i][r] + bb[1]);
        float gg = tanh_fast(acc[2][i][r] + bb[2]);
        float ov = sigf(acc[3 % NG][i][r] + bb[3 % NG]);
        int par = b * (M >> 1) + (m >> 1);
        float c2 = fv * cprev[(size_t)par * NH + hhL] + iv * gg;
        float h2 = ov * tanh_fast(c2);
        h_out[(size_t)row * NH + hhL] = f2bf(h2);          // ph for next level
        c_out[(size_t)row * NH + hhL] = c2;                // pc
      }
    }
  }
}

// ---- mega-pack: all weight packs + emb + ph/pc zero in ONE kernel ----
__global__ void mega_pack(
    const float* __restrict__ bu_Wioux, const float* __restrict__ bu_Wiouh,
    const float* __restrict__ bu_Wfx, const float* __restrict__ bu_Wfh,
    const float* __restrict__ bu_bioux, const float* __restrict__ bu_bfx,
    const float* __restrict__ bu_eWih, const float* __restrict__ bu_eWhh,
    const float* __restrict__ bu_ebih, const float* __restrict__ bu_ebhh,
    const float* __restrict__ td_Wioux, const float* __restrict__ td_Wiouhc,
    const float* __restrict__ td_Wiouhp, const float* __restrict__ td_Wfx,
    const float* __restrict__ td_Wfchild, const float* __restrict__ td_Wfparent,
    const float* __restrict__ td_bioux, const float* __restrict__ td_bfx,
    const float* __restrict__ td_eWih, const float* __restrict__ td_eWhh,
    const float* __restrict__ td_ebih, const float* __restrict__ td_ebhh,
    const float* __restrict__ ne, const float* __restrict__ ee,
    u16* __restrict__ Wbunh, float* __restrict__ bbun,
    u16* __restrict__ Wbueh, float* __restrict__ bbue,
    u16* __restrict__ Wtdnh, float* __restrict__ btdn,
    u16* __restrict__ Wtdeh, float* __restrict__ btde,
    u16* __restrict__ neb, u16* __restrict__ eeb,
    u16* __restrict__ ph_b, float* __restrict__ pc)
{
  int tid = blockIdx.x*256 + threadIdx.x;
  // TD node: rows [x|ph|cat] k-stride 1024; cols [iou|fpar|f0|f1]
  if (tid < 1024*1536){
    int n = tid / 1024, k = tid % 1024;
    float v;
    if (n < 768){
      v = (k < 256) ? td_Wioux[k*768 + n]
        : (k < 512) ? td_Wiouhp[(k-256)*768 + n]
                    : td_Wiouhc[(k-512)*768 + n];
    } else if (n < 1024){
      int nn = n - 768;
      v = (k < 256) ? td_Wfx[k*256 + nn] : td_Wfparent[(size_t)(k-256)*256 + nn];
    } else {
      int kidx = (n < 1280) ? 0 : 1;
      int nn = n - 1024 - kidx*256;
      v = (k < 256) ? td_Wfx[k*256 + nn]
                    : td_Wfchild[((size_t)kidx*768 + (k-256))*256 + nn];
    }
    Wtdnh[tid] = f2bf(v);
  }
  // BU node: rows [x|cat] k-stride 768; cols [iou|f0|f1]
  if (tid < 768*1280){
    int n = tid / 768, k = tid % 768;
    float v;
    if (n < 768){
      v = (k < 256) ? bu_Wioux[k*768 + n] : bu_Wiouh[(k-256)*768 + n];
    } else {
      int kidx = (n < 1024) ? 0 : 1;
      int nn = n - 768 - kidx*256;
      v = (k < 256) ? bu_Wfx[k*256 + nn] : bu_Wfh[((size_t)kidx*512 + (k-256))*256 + nn];
    }
    Wbunh[tid] = f2bf(v);
  }
  // both edges: rows [x|h] k-stride 512
  if (tid < 512*1024){
    int n = tid / 512, k = tid % 512;
    float v1 = (k < 256) ? bu_eWih[k*1024 + n] : bu_eWhh[(k-256)*1024 + n];
    float v2 = (k < 256) ? td_eWih[k*1024 + n] : td_eWhh[(k-256)*1024 + n];
    Wbueh[tid] = f2bf(v1);
    Wtdeh[tid] = f2bf(v2);
  }
  // biases
  if (tid < 1536) btdn[tid] = (tid < 768) ? td_bioux[tid] : td_bfx[(tid-768) & 255];
  if (tid < 1280) bbun[tid] = (tid < 768) ? bu_bioux[tid] : bu_bfx[(tid-768) & 255];
  if (tid < 1024){
    bbue[tid] = bu_ebih[tid] + bu_ebhh[tid];
    btde[tid] = td_ebih[tid] + td_ebhh[tid];
  }
  // embeddings + TD-root zero
  if (tid < 64*256)  neb[tid] = f2bf(ne[tid]);
  if (tid < 128*256) eeb[tid] = f2bf(ee[tid]);
  if (tid < NB*NH){ ph_b[tid] = 0; pc[tid] = 0.0f; }
}

// ---- fused LUT build #1: lut64 (BU node iou over 64 ids) + lutE (edge x) ----
__global__ void build_luts1(const u16* __restrict__ neb, const u16* __restrict__ eeb,
                            const u16* __restrict__ Wbunh, const float* __restrict__ bbun,
                            const u16* __restrict__ Wbueh, const float* __restrict__ bbue,
                            float* __restrict__ lut64, float* __restrict__ lutE)
{
  int t = blockIdx.x * 256 + threadIdx.x;
  if (t < 64*768){
    int id = t / 768, n = t % 768;
    const u16* e  = neb + id * 256;
    const u16* wv = Wbunh + (size_t)n * 768;
    float z = bbun[n];
    for (int k = 0; k < 256; k += 8){
      #pragma unroll
      for (int q = 0; q < 8; ++q) z += bf2f(e[k + q]) * bf2f(wv[k + q]);
    }
    lut64[((size_t)id * 256 + (n & 255)) * 3 + (n >> 8)] = z;
  } else if (t < 64*768 + 128*1024){
    int tt = t - 64*768;
    int id = tt / 1024, n = tt % 1024;
    const u16* e  = eeb + id * 256;
    const u16* wv = Wbueh + (size_t)n * 512;
    float z = bbue[n];
    for (int k = 0; k < 256; k += 8){
      #pragma unroll
      for (int q = 0; q < 8; ++q) z += bf2f(e[k + q]) * bf2f(wv[k + q]);
    }
    lutE[((size_t)id * 256 + (n & 255)) * 4 + (n >> 8)] = z;
  }
}

__global__ void build_leaf(const float* __restrict__ lut64,
                           float* __restrict__ c64, float* __restrict__ h64f,
                           u16* __restrict__ h64b)
{
  int t = blockIdx.x * 256 + threadIdx.x;     // 64*256
  const float* lp = lut64 + (size_t)t * 3;
  float iv = sigf(lp[0]), ov = sigf(lp[1]), uv = tanh_fast(lp[2]);
  float c = iv * uv;
  float h = ov * tanh_fast(c);
  c64[t] = c; h64f[t] = h; h64b[t] = f2bf(h);
}

// lutH[id][hh][4] = h_leaf[id] @ Whh (k-offset 256, no bias)
__global__ void build_lutH(const u16* __restrict__ h64b,
                           const u16* __restrict__ Wbueh,
                           float* __restrict__ lutH)
{
  int t = blockIdx.x * 256 + threadIdx.x;     // 64*1024
  int id = t / 1024, n = t % 1024;
  const u16* e  = h64b + id * 256;
  const u16* wv = Wbueh + (size_t)n * 512 + 256;
  float z = 0.0f;
  for (int k = 0; k < 256; k += 8){
    #pragma unroll
    for (int q = 0; q < 8; ++q) z += bf2f(e[k + q]) * bf2f(wv[k + q]);
  }
  lutH[((size_t)id * 256 + (n & 255)) * 4 + (n >> 8)] = z;
}

// BU leaf: node-out gather + collapsed edge-LSTM in ONE kernel.
__global__ void leaf_edge(const int* __restrict__ node_ids,
                          const int* __restrict__ edge_ids,
                          const float* __restrict__ lutE,   // [128][256][4] (bias in)
                          const float* __restrict__ lutH,   // [64][256][4]
                          const float* __restrict__ c64,
                          const float* __restrict__ h64f,
                          u16* __restrict__ he_b, float* __restrict__ ce_all,
                          float* __restrict__ out)
{
  int gr = blockIdx.x;                        // leaf row 0..32767
  int hh = threadIdx.x;
  int b = gr >> 11, m = gr & 2047;
  int j = 2047 + m;
  int nid = node_ids[b * NN + j];
  int eid = edge_ids[b * NN + j];
  // node out (was leaf_gather)
  out[((size_t)(b * NN + j)) * OUTW + hh] = h64f[nid * 256 + hh];
  // collapsed edge-LSTM
  float4 ge = *(const float4*)(lutE + ((size_t)eid * 256 + hh) * 4);
  float4 gh = *(const float4*)(lutH + ((size_t)nid * 256 + hh) * 4);
  float iv = sigf(ge.x + gh.x);               // gate order [i|f|g|o]
  float fv = sigf(ge.y + gh.y);
  float gg = tanh_fast(ge.z + gh.z);
  float ov = sigf(ge.w + gh.w);
  float cp = c64[nid * 256 + hh];
  float c2 = fv * cp + iv * gg;
  float h2 = ov * tanh_fast(c2);
  size_t di = ((size_t)(b * NN + j)) * NH + hh;
  he_b[di] = f2bf(h2);
  ce_all[di] = c2;
}

extern "C" void kernel_launch(void* const* d_in, const int* in_sizes, int n_in,
                              void* d_out, int out_size, void* d_ws, size_t ws_size,
                              hipStream_t stream)
{
  const float* node_emb  = (const float*)d_in[0];
  const float* edge_emb  = (const float*)d_in[1];
  const float* bu_Wioux  = (const float*)d_in[2];
  const float* bu_bioux  = (const float*)d_in[3];
  const float* bu_Wfx    = (const float*)d_in[4];
  const float* bu_bfx    = (const float*)d_in[5];
  const float* bu_Wiouh  = (const float*)d_in[6];
  const float* bu_Wfh    = (const float*)d_in[7];
  const float* bu_eWih   = (const float*)d_in[8];
  const float* bu_eWhh   = (const float*)d_in[9];
  const float* bu_ebih   = (const float*)d_in[10];
  const float* bu_ebhh   = (const float*)d_in[11];
  const float* td_Wioux  = (const float*)d_in[12];
  const float* td_bioux  = (const float*)d_in[13];
  const float* td_Wfx    = (const float*)d_in[14];
  const float* td_bfx    = (const float*)d_in[15];
  const float* td_Wiouhc = (const float*)d_in[16];
  const float* td_Wiouhp = (const float*)d_in[17];
  const float* td_Wfchild= (const float*)d_in[18];
  const float* td_Wfparent=(const float*)d_in[19];
  const float* td_eWih   = (const float*)d_in[20];
  const float* td_eWhh   = (const float*)d_in[21];
  const float* td_ebih   = (const float*)d_in[22];
  const float* td_ebhh   = (const float*)d_in[23];
  const int* node_ids    = (const int*)d_in[24];
  const int* edge_ids    = (const int*)d_in[25];
  float* out = (float*)d_out;

  // ---- workspace ----
  float* fw = (float*)d_ws;
  size_t fo = 0;
  float* bbun = fw + fo; fo += 1280;
  float* bbue = fw + fo; fo += 1024;
  float* btdn = fw + fo; fo += 1536;
  float* btde = fw + fo; fo += 1024;
  float* lut64 = fw + fo; fo += (size_t)64*256*3;
  float* c64  = fw + fo; fo += (size_t)64*256;
  float* h64f = fw + fo; fo += (size_t)64*256;
  float* lutE = fw + fo; fo += (size_t)128*256*4;
  float* lutH = fw + fo; fo += (size_t)64*256*4;
  float* ce_all = fw + fo; fo += (size_t)NB*NN*NH;
  float* c_lvl  = fw + fo; fo += (size_t)NB*2048*NH;
  float* pc     = fw + fo; fo += (size_t)NB*2048*NH;

  u16* uw = (u16*)(fw + fo);
  size_t uo = 0;
  u16* Wbunh = uw + uo; uo += (size_t)768*1280;
  u16* Wbueh = uw + uo; uo += (size_t)512*1024;
  u16* Wtdnh = uw + uo; uo += (size_t)1024*1536;
  u16* Wtdeh = uw + uo; uo += (size_t)512*1024;
  u16* neb = uw + uo; uo += (size_t)64*256;
  u16* eeb = uw + uo; uo += (size_t)128*256;
  u16* h64b = uw + uo; uo += (size_t)64*256;
  u16* he_b = uw + uo; uo += (size_t)NB*NN*NH;
  u16* hl_b = uw + uo; uo += (size_t)NB*2048*NH;
  u16* ph_b = uw + uo; uo += (size_t)NB*2048*NH;

  // ---- pack (1 launch) ----
  mega_pack<<<(1024*1536+255)/256, 256, 0, stream>>>(
      bu_Wioux, bu_Wiouh, bu_Wfx, bu_Wfh, bu_bioux, bu_bfx,
      bu_eWih, bu_eWhh, bu_ebih, bu_ebhh,
      td_Wioux, td_Wiouhc, td_Wiouhp, td_Wfx, td_Wfchild, td_Wfparent,
      td_bioux, td_bfx, td_eWih, td_eWhh, td_ebih, td_ebhh,
      node_emb, edge_emb,
      Wbunh, bbun, Wbueh, bbue, Wtdnh, btdn, Wtdeh, btde,
      neb, eeb, ph_b, pc);

  // ---- BU leaf tables (3 launches) ----
  build_luts1<<<(64*768 + 128*1024 + 255)/256, 256, 0, stream>>>(
      neb, eeb, Wbunh, bbun, Wbueh, bbue, lut64, lutE);
  build_leaf<<<64, 256, 0, stream>>>(lut64, c64, h64f, h64b);
  build_lutH<<<(64*1024)/256, 256, 0, stream>>>(h64b, Wbueh, lutH);

  // ---------- bottom-up ----------
  {   // leaf level l=11: node gather + collapsed edge-LSTM, one kernel
    int R = NB * 2048;
    leaf_edge<<<R, 256, 0, stream>>>(node_ids, edge_ids, lutE, lutH, c64, h64f,
        he_b, ce_all, out);
  }
  for (int l = NLV-2; l >= 0; --l){
    int M = 1<<l, s = M-1, R = NB*M;
    dim3 grid((R + 127) / 128, NH / 32);
    if (l > 0){
      fused_gemm<0,5><<<grid, 256, 0, stream>>>(R, l, s, node_ids,
          neb, he_b, neb, Wbunh, 768, bbun,
          ce_all, nullptr, c_lvl, hl_b, out);
      fused_gemm<1,4><<<grid, 256, 0, stream>>>(R, l, s, edge_ids,
          eeb, hl_b, neb, Wbueh, 512, bbue,
          nullptr, c_lvl, ce_all, he_b, nullptr);
    } else {
      // BU l=0: state writes dead (edge skipped; TD l=0 overwrites first)
      fused_gemm<0,5,false><<<grid, 256, 0, stream>>>(R, l, s, node_ids,
          neb, he_b, neb, Wbunh, 768, bbun,
          ce_all, nullptr, c_lvl, hl_b, out);
    }
  }

  // ---------- top-down ----------
  for (int l = 0; l < NLV; ++l){
    int M = 1<<l, s = M-1, R = NB*M;
    bool leaf = (l == NLV-1);
    dim3 grid((R + 127) / 128, NH / 32);
    if (!leaf){
      fused_gemm<2,6><<<grid, 256, 0, stream>>>(R, l, s, node_ids,
          neb, ph_b, he_b, Wtdnh, 1024, btdn,
          ce_all, pc, c_lvl, hl_b, out);
      int M2 = 2*M, s2 = 2*M-1, R2 = NB*M2;
      dim3 grid2((R2 + 127) / 128, NH / 32);
      fused_gemm<3,4><<<grid2, 256, 0, stream>>>(R2, l+1, s2, edge_ids,
          eeb, hl_b, neb, Wtdeh, 512, btde,
          nullptr, c_lvl, pc, ph_b, nullptr);
    } else {
      // TD leaf: c_lvl/hl_b never read afterwards -> skip state writes
      fused_gemm<2,4,false><<<grid, 256, 0, stream>>>(R, l, s, node_ids,
          neb, ph_b, neb, Wtdnh, 1024, btdn,
          nullptr, pc, c_lvl, hl_b, out);
    }
  }
}